// Round 1
// baseline (491.836 us; speedup 1.0000x reference)
//
#include <hip/hip_runtime.h>
#include <hip/hip_bf16.h>

typedef unsigned short u16;
typedef unsigned int u32;
typedef __attribute__((ext_vector_type(4))) float f32x4;
typedef __attribute__((ext_vector_type(8))) short s16x8;

#define NB 2
#define NT 2048
#define ND 2048
#define NH 16
#define NKV 4
#define NHD 128

__device__ __forceinline__ u16 f2bf(float f) {
  u32 u = __builtin_bit_cast(u32, f);
  u32 r = u + 0x7fffu + ((u >> 16) & 1u);
  return (u16)(r >> 16);
}
__device__ __forceinline__ float bf2f(u16 h) {
  return __builtin_bit_cast(float, (u32)h << 16);
}
__device__ __forceinline__ void store_c(float* p, float v) { *p = v; }
__device__ __forceinline__ void store_c(u16* p, float v) { *p = f2bf(v); }

// ---------------- f32 -> bf16 conversion ----------------
__global__ void cvt_kernel(const float* __restrict__ src, u16* __restrict__ dst, long n4) {
  long stride = (long)gridDim.x * blockDim.x;
  for (long i = (long)blockIdx.x * blockDim.x + threadIdx.x; i < n4; i += stride) {
    float4 v = *(const float4*)(src + i * 4);
    ushort4 o;
    o.x = f2bf(v.x); o.y = f2bf(v.y); o.z = f2bf(v.z); o.w = f2bf(v.w);
    *(ushort4*)(dst + i * 4) = o;
  }
}

// ---------------- RoPE table ----------------
__global__ void rope_table_kernel(float* __restrict__ cs, float* __restrict__ sn) {
  int idx = blockIdx.x * blockDim.x + threadIdx.x;
  if (idx >= NT * 64) return;
  int t = idx >> 6, j = idx & 63;
  float invf = expf(-(float)(2 * j) * (9.210340371976184f / 128.0f)); // 10000^(-2j/128)
  float f = (float)t * invf;
  cs[idx] = cosf(f);
  sn[idx] = sinf(f);
}

// ---------------- GEMM: C[M][N] = A[M][K] * B[N][K]^T, bf16 in, OT out ----------------
template <typename OT>
__global__ __launch_bounds__(256, 2)
void gemm_bt_kernel(const u16* __restrict__ A, const u16* __restrict__ Bm,
                    OT* __restrict__ C, int M, int N, int K) {
  __shared__ u16 As[128][40];  // stride 80B = 5*16B: aligned b128, 2-way banks (free)
  __shared__ u16 Bs[128][40];
  int ntn = N >> 7;
  int bm = blockIdx.x / ntn, bn = blockIdx.x % ntn;
  int tid = threadIdx.x;
  int lane = tid & 63;
  int wid = tid >> 6;
  int wm = wid >> 1, wn = wid & 1;          // 2x2 waves, each 64x64
  int srow = tid >> 2, scol = (tid & 3) << 3;
  const u16* Ab = A + (long)bm * 128 * K;
  const u16* Bb = Bm + (long)bn * 128 * K;
  f32x4 acc[4][4];
#pragma unroll
  for (int i = 0; i < 4; i++)
#pragma unroll
    for (int j = 0; j < 4; j++) acc[i][j] = (f32x4){0.f, 0.f, 0.f, 0.f};
  int r = lane & 15, kg = lane >> 4;
  for (int k0 = 0; k0 < K; k0 += 32) {
    s16x8 a0 = *(const s16x8*)(Ab + (long)srow * K + k0 + scol);
    s16x8 a1 = *(const s16x8*)(Ab + (long)(srow + 64) * K + k0 + scol);
    s16x8 b0 = *(const s16x8*)(Bb + (long)srow * K + k0 + scol);
    s16x8 b1 = *(const s16x8*)(Bb + (long)(srow + 64) * K + k0 + scol);
    __syncthreads();
    *(s16x8*)(&As[srow][scol]) = a0;
    *(s16x8*)(&As[srow + 64][scol]) = a1;
    *(s16x8*)(&Bs[srow][scol]) = b0;
    *(s16x8*)(&Bs[srow + 64][scol]) = b1;
    __syncthreads();
    s16x8 af[4], bf[4];
#pragma unroll
    for (int i = 0; i < 4; i++) af[i] = *(const s16x8*)(&As[wm * 64 + i * 16 + r][kg * 8]);
#pragma unroll
    for (int i = 0; i < 4; i++) bf[i] = *(const s16x8*)(&Bs[wn * 64 + i * 16 + r][kg * 8]);
#pragma unroll
    for (int i = 0; i < 4; i++)
#pragma unroll
      for (int j = 0; j < 4; j++)
        acc[i][j] = __builtin_amdgcn_mfma_f32_16x16x32_bf16(af[i], bf[j], acc[i][j], 0, 0, 0);
  }
  // C/D layout: col = lane&15, row = (lane>>4)*4 + reg  [verified m89/m91]
#pragma unroll
  for (int i = 0; i < 4; i++) {
    int row0 = bm * 128 + wm * 64 + i * 16 + kg * 4;
#pragma unroll
    for (int j = 0; j < 4; j++) {
      int col = bn * 128 + wn * 64 + j * 16 + r;
#pragma unroll
      for (int e = 0; e < 4; e++) store_c(&C[(long)(row0 + e) * N + col], acc[i][j][e]);
    }
  }
}

// ---------------- RoPE + rearrange ----------------
__global__ void rope_q_kernel(const u16* __restrict__ qkv, const float* __restrict__ cs,
                              const float* __restrict__ sn, u16* __restrict__ Qr) {
  int idx = blockIdx.x * blockDim.x + threadIdx.x; // NB*NT*NH*64
  int j = idx & 63;
  int h = (idx >> 6) & (NH - 1);
  int t = (idx >> 10) & (NT - 1);
  int b = idx >> 21;
  const u16* row = qkv + (long)(b * NT + t) * 3072 + h * 128;
  float x1 = bf2f(row[j]), x2 = bf2f(row[j + 64]);
  float c = cs[t * 64 + j], s = sn[t * 64 + j];
  u16* orow = Qr + ((long)((b * NH + h) * NT + t)) * 128;
  orow[j] = f2bf(x1 * c - x2 * s);
  orow[j + 64] = f2bf(x2 * c + x1 * s);
}

__global__ void rope_k_kernel(const u16* __restrict__ qkv, const float* __restrict__ cs,
                              const float* __restrict__ sn, u16* __restrict__ Kr) {
  int idx = blockIdx.x * blockDim.x + threadIdx.x; // NB*NT*NKV*64
  int j = idx & 63;
  int kv = (idx >> 6) & 3;
  int t = (idx >> 8) & (NT - 1);
  int b = idx >> 19;
  const u16* row = qkv + (long)(b * NT + t) * 3072 + 2048 + kv * 128;
  float x1 = bf2f(row[j]), x2 = bf2f(row[j + 64]);
  float c = cs[t * 64 + j], s = sn[t * 64 + j];
  u16* orow = Kr + ((long)((b * NKV + kv) * NT + t)) * 128;
  orow[j] = f2bf(x1 * c - x2 * s);
  orow[j + 64] = f2bf(x2 * c + x1 * s);
}

__global__ void copy_v_kernel(const u16* __restrict__ qkv, u16* __restrict__ Vr) {
  int idx = blockIdx.x * blockDim.x + threadIdx.x; // NB*NT*NKV*16
  int dc = idx & 15;
  int kv = (idx >> 4) & 3;
  int t = (idx >> 6) & (NT - 1);
  int b = idx >> 17;
  s16x8 v = *(const s16x8*)(qkv + (long)(b * NT + t) * 3072 + 2560 + kv * 128 + dc * 8);
  *(s16x8*)(Vr + ((long)((b * NKV + kv) * NT + t)) * 128 + dc * 8) = v;
}

// ---------------- Flash attention (non-causal, GQA) ----------------
__global__ __launch_bounds__(256, 2)
void attn_kernel(const u16* __restrict__ Qr, const u16* __restrict__ Kr,
                 const u16* __restrict__ Vr, u16* __restrict__ Ao) {
  __shared__ u16 Ks[64 * 128];  // [kv_t][d], XOR-swizzled 16B chunks
  __shared__ u16 Vt[128 * 64];  // [d][kv_t], XOR-swizzled
  __shared__ u16 Ps[64 * 64];   // [q_row][kv_t], XOR-swizzled
  const float scale = 0.0883883476483184f; // 1/sqrt(128)
  int blk = blockIdx.x;
  int qt = blk & 31;
  int h = (blk >> 5) & (NH - 1);
  int b = blk >> 9;
  int kvh = h >> 2; // h / (H/KV)
  int tid = threadIdx.x, lane = tid & 63, wid = tid >> 6;
  int r = lane & 15, kg = lane >> 4;
  const u16* Qbase = Qr + ((long)((b * NH + h) * NT) + qt * 64 + wid * 16) * 128;
  s16x8 qf[4];
#pragma unroll
  for (int i = 0; i < 4; i++) qf[i] = *(const s16x8*)(Qbase + (long)r * 128 + i * 32 + kg * 8);
  const u16* Kb = Kr + (long)(b * NKV + kvh) * NT * 128;
  const u16* Vb = Vr + (long)(b * NKV + kvh) * NT * 128;
  f32x4 o[8];
#pragma unroll
  for (int n = 0; n < 8; n++) o[n] = (f32x4){0.f, 0.f, 0.f, 0.f};
  float mrow[4] = {-1e30f, -1e30f, -1e30f, -1e30f};
  float lrow[4] = {0.f, 0.f, 0.f, 0.f};
  char* KsB = (char*)Ks;
  char* VtB = (char*)Vt;
  char* PsB = (char*)Ps;

  for (int kt = 0; kt < NT; kt += 64) {
    __syncthreads(); // protect prior tile reads
    // stage K tile [64][128], coalesced global, swizzled LDS
#pragma unroll
    for (int p = 0; p < 4; p++) {
      int krow = p * 16 + (tid >> 4);
      int c16 = tid & 15;
      s16x8 v = *(const s16x8*)(Kb + (long)(kt + krow) * 128 + c16 * 8);
      *(s16x8*)(KsB + krow * 256 + (((c16) ^ (krow & 7)) << 4)) = v;
    }
    // stage V transposed: Vt[d][t]
#pragma unroll
    for (int p = 0; p < 4; p++) {
      int trow = tid & 63;
      int dc = (tid >> 6) + p * 4;
      s16x8 v = *(const s16x8*)(Vb + (long)(kt + trow) * 128 + dc * 8);
#pragma unroll
      for (int e = 0; e < 8; e++) {
        int d = dc * 8 + e;
        int off = (d * 128 + trow * 2) ^ ((d & 7) << 4);
        *(u16*)(VtB + off) = (u16)(unsigned short)v[e];
      }
    }
    __syncthreads();
    // S = Q K^T : each wave 16 rows x 64 kv
    f32x4 sc[4];
#pragma unroll
    for (int n = 0; n < 4; n++) sc[n] = (f32x4){0.f, 0.f, 0.f, 0.f};
#pragma unroll
    for (int i = 0; i < 4; i++) {
#pragma unroll
      for (int n = 0; n < 4; n++) {
        int row = n * 16 + r;
        s16x8 kf = *(const s16x8*)(KsB + row * 256 + (((i * 4 + kg) ^ (row & 7)) << 4));
        sc[n] = __builtin_amdgcn_mfma_f32_16x16x32_bf16(qf[i], kf, sc[n], 0, 0, 0);
      }
    }
    // online softmax (rows = kg*4+e within wave tile; reduce across lanes 0-15)
#pragma unroll
    for (int e = 0; e < 4; e++) {
      float mx = fmaxf(fmaxf(sc[0][e], sc[1][e]), fmaxf(sc[2][e], sc[3][e]));
#pragma unroll
      for (int msk = 1; msk < 16; msk <<= 1) mx = fmaxf(mx, __shfl_xor(mx, msk, 64));
      float pm = mx * scale;
      float mnew = fmaxf(mrow[e], pm);
      float corr = __expf(mrow[e] - mnew);
      mrow[e] = mnew;
      float rs = 0.f;
      int prow = wid * 16 + kg * 4 + e;
#pragma unroll
      for (int n = 0; n < 4; n++) {
        float p = __expf(sc[n][e] * scale - mnew);
        rs += p;
        int off = (prow * 128 + (n * 16 + r) * 2) ^ ((prow & 7) << 4);
        *(u16*)(PsB + off) = f2bf(p);
      }
#pragma unroll
      for (int msk = 1; msk < 16; msk <<= 1) rs += __shfl_xor(rs, msk, 64);
      lrow[e] = lrow[e] * corr + rs;
#pragma unroll
      for (int n = 0; n < 8; n++) o[n][e] *= corr;
    }
    __syncthreads(); // make P visible (paranoia: same-wave LDS RAW)
    // O += P V : A = Ps rows (wave's 16), B = Vt
#pragma unroll
    for (int i = 0; i < 2; i++) {
      int prow = wid * 16 + r;
      s16x8 pf = *(const s16x8*)(PsB + prow * 128 + (((i * 4 + kg) ^ (prow & 7)) << 4));
#pragma unroll
      for (int n = 0; n < 8; n++) {
        int drow = n * 16 + r;
        s16x8 vf = *(const s16x8*)(VtB + drow * 128 + (((i * 4 + kg) ^ (drow & 7)) << 4));
        o[n] = __builtin_amdgcn_mfma_f32_16x16x32_bf16(pf, vf, o[n], 0, 0, 0);
      }
    }
  }
  // epilogue: normalize and store to [b*T + row][h*128 + d]
#pragma unroll
  for (int e = 0; e < 4; e++) {
    float inv = 1.0f / lrow[e];
    int row = qt * 64 + wid * 16 + kg * 4 + e;
    u16* orow = Ao + (long)(b * NT + row) * ND + h * 128;
#pragma unroll
    for (int n = 0; n < 8; n++) orow[n * 16 + r] = f2bf(o[n][e] * inv);
  }
}

// ---------------- launch ----------------
extern "C" void kernel_launch(void* const* d_in, const int* in_sizes, int n_in,
                              void* d_out, int out_size, void* d_ws, size_t ws_size,
                              hipStream_t stream) {
  const float* x  = (const float*)d_in[0];
  const float* wq = (const float*)d_in[1];
  const float* wk = (const float*)d_in[2];
  const float* wv = (const float*)d_in[3];
  const float* wo = (const float*)d_in[4];
  char* ws = (char*)d_ws;
  size_t off = 0;
  auto alloc = [&](size_t bytes) {
    char* p = ws + off;
    off += (bytes + 255) & ~(size_t)255;
    return p;
  };
  u16* xb    = (u16*)alloc((size_t)4096 * 2048 * 2);
  u16* wqkvb = (u16*)alloc((size_t)3072 * 2048 * 2);
  u16* wob   = (u16*)alloc((size_t)2048 * 2048 * 2);
  u16* qkv   = (u16*)alloc((size_t)4096 * 3072 * 2);
  float* cs  = (float*)alloc((size_t)2048 * 64 * 4);
  float* sn  = (float*)alloc((size_t)2048 * 64 * 4);
  u16* Qr    = (u16*)alloc((size_t)2 * 16 * 2048 * 128 * 2);
  u16* Kr    = (u16*)alloc((size_t)2 * 4 * 2048 * 128 * 2);
  u16* Vr    = (u16*)alloc((size_t)2 * 4 * 2048 * 128 * 2);
  u16* Ao    = qkv; // qkv is dead after rearrange; reuse for attention output

  cvt_kernel<<<dim3(2048), dim3(256), 0, stream>>>(x, xb, 4096L * 2048 / 4);
  cvt_kernel<<<dim3(1024), dim3(256), 0, stream>>>(wq, wqkvb, 2048L * 2048 / 4);
  cvt_kernel<<<dim3(256), dim3(256), 0, stream>>>(wk, wqkvb + 2048L * 2048, 512L * 2048 / 4);
  cvt_kernel<<<dim3(256), dim3(256), 0, stream>>>(wv, wqkvb + 2560L * 2048, 512L * 2048 / 4);
  cvt_kernel<<<dim3(1024), dim3(256), 0, stream>>>(wo, wob, 2048L * 2048 / 4);
  rope_table_kernel<<<dim3(512), dim3(256), 0, stream>>>(cs, sn);
  gemm_bt_kernel<u16><<<dim3(32 * 24), dim3(256), 0, stream>>>(xb, wqkvb, qkv, 4096, 3072, 2048);
  rope_q_kernel<<<dim3(16384), dim3(256), 0, stream>>>(qkv, cs, sn, Qr);
  rope_k_kernel<<<dim3(4096), dim3(256), 0, stream>>>(qkv, cs, sn, Kr);
  copy_v_kernel<<<dim3(1024), dim3(256), 0, stream>>>(qkv, Vr);
  attn_kernel<<<dim3(1024), dim3(256), 0, stream>>>(Qr, Kr, Vr, Ao);
  gemm_bt_kernel<float><<<dim3(32 * 16), dim3(256), 0, stream>>>(Ao, wob, (float*)d_out, 4096, 2048, 2048);
}

// Round 3
// 437.128 us; speedup vs baseline: 1.1252x; 1.1252x over previous
//
#include <hip/hip_runtime.h>
#include <hip/hip_bf16.h>

typedef unsigned short u16;
typedef unsigned int u32;
typedef __attribute__((ext_vector_type(4))) float f32x4;
typedef __attribute__((ext_vector_type(8))) short s16x8;
typedef __attribute__((ext_vector_type(2))) unsigned int u32x2;
typedef __attribute__((ext_vector_type(4))) unsigned int u32x4;

#define NB 2
#define NT 2048
#define ND 2048
#define NH 16
#define NKV 4
#define NHD 128

#define LDSOFF(p) ((unsigned)(size_t)(__attribute__((address_space(3))) void*)(p))

__device__ __forceinline__ u16 f2bf(float f) {
  u32 u = __builtin_bit_cast(u32, f);
  u32 r = u + 0x7fffu + ((u >> 16) & 1u);
  return (u16)(r >> 16);
}
__device__ __forceinline__ float bf2f(u16 h) {
  return __builtin_bit_cast(float, (u32)h << 16);
}
__device__ __forceinline__ void store_c(float* p, float v) { *p = v; }
__device__ __forceinline__ void store_c(u16* p, float v) { *p = f2bf(v); }

__device__ __forceinline__ void gll16(const u16* g, u16* l) {
  __builtin_amdgcn_global_load_lds(
      (const __attribute__((address_space(1))) u32*)(g),
      (__attribute__((address_space(3))) u32*)(l), 16, 0, 0);
}

// ---------------- f32 -> bf16 conversion ----------------
__global__ void cvt_kernel(const float* __restrict__ src, u16* __restrict__ dst, long n4) {
  long stride = (long)gridDim.x * blockDim.x;
  for (long i = (long)blockIdx.x * blockDim.x + threadIdx.x; i < n4; i += stride) {
    float4 v = *(const float4*)(src + i * 4);
    ushort4 o;
    o.x = f2bf(v.x); o.y = f2bf(v.y); o.z = f2bf(v.z); o.w = f2bf(v.w);
    *(ushort4*)(dst + i * 4) = o;
  }
}

// ---------------- RoPE table ----------------
__global__ void rope_table_kernel(float* __restrict__ cs, float* __restrict__ sn) {
  int idx = blockIdx.x * blockDim.x + threadIdx.x;
  if (idx >= NT * 64) return;
  int t = idx >> 6, j = idx & 63;
  float invf = expf(-(float)(2 * j) * (9.210340371976184f / 128.0f)); // 10000^(-2j/128)
  float f = (float)t * invf;
  cs[idx] = cosf(f);
  sn[idx] = sinf(f);
}

// ---------------- GEMM: C[M][N] = A[M][K] * B[N][K]^T (m97 structure) ----------------
template <typename OT>
__global__ __launch_bounds__(256, 3)
void gemm_bt_kernel(const u16* __restrict__ A, const u16* __restrict__ Bm,
                    OT* __restrict__ C, int M, int N, int K) {
  __shared__ __align__(16) u16 As[128 * 32];  // [row][32] linear, 64B rows
  __shared__ __align__(16) u16 Bs[128 * 32];
  int nwg = gridDim.x;
  int bid = (blockIdx.x & 7) * (nwg >> 3) + (blockIdx.x >> 3);  // XCD swizzle (nwg%8==0)
  int ntn = N >> 7;
  int bm = bid / ntn, bn = bid % ntn;
  int tid = threadIdx.x;
  int lane = tid & 63;
  int wid = tid >> 6;
  int wm = wid >> 1, wn = wid & 1;  // 2x2 waves, each 64x64
  int r = lane & 15, kg = lane >> 4;
  const u16* Ag = A + (long)(bm * 128 + wid * 32 + (lane >> 2)) * K + (lane & 3) * 8;
  const u16* Bg = Bm + (long)(bn * 128 + wid * 32 + (lane >> 2)) * K + (lane & 3) * 8;
  char* AsB = (char*)As;
  char* BsB = (char*)Bs;
  u16* Ald0 = As + (wid * 32) * 32;
  u16* Ald1 = As + (wid * 32 + 16) * 32;
  u16* Bld0 = Bs + (wid * 32) * 32;
  u16* Bld1 = Bs + (wid * 32 + 16) * 32;
  f32x4 acc[4][4];
#pragma unroll
  for (int i = 0; i < 4; i++)
#pragma unroll
    for (int j = 0; j < 4; j++) acc[i][j] = (f32x4){0.f, 0.f, 0.f, 0.f};
  for (int k0 = 0; k0 < K; k0 += 32) {
    __syncthreads();
    gll16(Ag + k0, Ald0);
    gll16(Ag + 16 * K + k0, Ald1);
    gll16(Bg + k0, Bld0);
    gll16(Bg + 16 * K + k0, Bld1);
    __syncthreads();
    s16x8 af[4], bf[4];
#pragma unroll
    for (int i = 0; i < 4; i++) af[i] = *(const s16x8*)(AsB + (wm * 64 + i * 16 + r) * 64 + kg * 16);
#pragma unroll
    for (int j = 0; j < 4; j++) bf[j] = *(const s16x8*)(BsB + (wn * 64 + j * 16 + r) * 64 + kg * 16);
#pragma unroll
    for (int i = 0; i < 4; i++)
#pragma unroll
      for (int j = 0; j < 4; j++)
        acc[i][j] = __builtin_amdgcn_mfma_f32_16x16x32_bf16(af[i], bf[j], acc[i][j], 0, 0, 0);
  }
  // C/D layout: col = lane&15, row = (lane>>4)*4 + reg
#pragma unroll
  for (int i = 0; i < 4; i++) {
    int row0 = bm * 128 + wm * 64 + i * 16 + kg * 4;
#pragma unroll
    for (int j = 0; j < 4; j++) {
      int col = bn * 128 + wn * 64 + j * 16 + r;
#pragma unroll
      for (int e = 0; e < 4; e++) store_c(&C[(long)(row0 + e) * N + col], acc[i][j][e]);
    }
  }
}

// ---------------- RoPE + rearrange (vectorized x2) ----------------
__global__ void rope_q_kernel(const u16* __restrict__ qkv, const float* __restrict__ cs,
                              const float* __restrict__ sn, u16* __restrict__ Qr) {
  int idx = blockIdx.x * blockDim.x + threadIdx.x;  // NB*NT*NH*32
  int j = (idx & 31) * 2;
  int h = (idx >> 5) & 15;
  int t = (idx >> 9) & 2047;
  int b = idx >> 20;
  const u16* row = qkv + (long)(b * NT + t) * 3072 + h * 128;
  u32 x1p = *(const u32*)(row + j);
  u32 x2p = *(const u32*)(row + j + 64);
  float2 cp = *(const float2*)(cs + t * 64 + j);
  float2 sp = *(const float2*)(sn + t * 64 + j);
  float x1a = bf2f((u16)x1p), x1b = bf2f((u16)(x1p >> 16));
  float x2a = bf2f((u16)x2p), x2b = bf2f((u16)(x2p >> 16));
  u16* orow = Qr + ((long)((b * NH + h) * NT + t)) * 128;
  u32 o1 = (u32)f2bf(x1a * cp.x - x2a * sp.x) | ((u32)f2bf(x1b * cp.y - x2b * sp.y) << 16);
  u32 o2 = (u32)f2bf(x2a * cp.x + x1a * sp.x) | ((u32)f2bf(x2b * cp.y + x1b * sp.y) << 16);
  *(u32*)(orow + j) = o1;
  *(u32*)(orow + j + 64) = o2;
}

__global__ void rope_k_kernel(const u16* __restrict__ qkv, const float* __restrict__ cs,
                              const float* __restrict__ sn, u16* __restrict__ Kr) {
  int idx = blockIdx.x * blockDim.x + threadIdx.x;  // NB*NT*NKV*32
  int j = (idx & 31) * 2;
  int kv = (idx >> 5) & 3;
  int t = (idx >> 7) & 2047;
  int b = idx >> 18;
  const u16* row = qkv + (long)(b * NT + t) * 3072 + 2048 + kv * 128;
  u32 x1p = *(const u32*)(row + j);
  u32 x2p = *(const u32*)(row + j + 64);
  float2 cp = *(const float2*)(cs + t * 64 + j);
  float2 sp = *(const float2*)(sn + t * 64 + j);
  float x1a = bf2f((u16)x1p), x1b = bf2f((u16)(x1p >> 16));
  float x2a = bf2f((u16)x2p), x2b = bf2f((u16)(x2p >> 16));
  u16* orow = Kr + ((long)((b * NKV + kv) * NT + t)) * 128;
  u32 o1 = (u32)f2bf(x1a * cp.x - x2a * sp.x) | ((u32)f2bf(x1b * cp.y - x2b * sp.y) << 16);
  u32 o2 = (u32)f2bf(x2a * cp.x + x1a * sp.x) | ((u32)f2bf(x2b * cp.y + x1b * sp.y) << 16);
  *(u32*)(orow + j) = o1;
  *(u32*)(orow + j + 64) = o2;
}

__global__ void copy_v_kernel(const u16* __restrict__ qkv, u16* __restrict__ Vr) {
  int idx = blockIdx.x * blockDim.x + threadIdx.x;  // NB*NT*NKV*16
  int dc = idx & 15;
  int kv = (idx >> 4) & 3;
  int t = (idx >> 6) & 2047;
  int b = idx >> 17;
  s16x8 v = *(const s16x8*)(qkv + (long)(b * NT + t) * 3072 + 2560 + kv * 128 + dc * 8);
  *(s16x8*)(Vr + ((long)((b * NKV + kv) * NT + t)) * 128 + dc * 8) = v;
}

// ---------------- Flash attention (non-causal, GQA) ----------------
// K: [64][128] XOR-swizzled rows.  V: 4x16 tr-tiles, tile(s4,d16) at byte s4*1056 + d16*128.
// P: [64][128B] XOR-swizzled (wave-private quadrants).
__global__ __launch_bounds__(256, 3)
void attn_kernel(const u16* __restrict__ Qr, const u16* __restrict__ Kr,
                 const u16* __restrict__ Vr, u16* __restrict__ Ao) {
  __shared__ __align__(16) u16 Ks[64 * 128];
  __shared__ __align__(16) u16 Vs[8448];     // 16*1056 bytes
  __shared__ __align__(16) u16 Ps[64 * 64];
  const float scale = 0.0883883476483184f;  // 1/sqrt(128)
  int blk = (blockIdx.x & 7) * 128 + (blockIdx.x >> 3);  // XCD swizzle: 1 (b,kvh) per XCD
  int qt = blk & 31;
  int h = (blk >> 5) & 15;
  int b = blk >> 9;
  int kvh = h >> 2;
  int tid = threadIdx.x, lane = tid & 63, wid = tid >> 6;
  int r = lane & 15, kg = lane >> 4;
  char* KsB = (char*)Ks;
  char* VsB = (char*)Vs;
  char* PsB = (char*)Ps;
  unsigned vsb = LDSOFF(Vs);

  const u16* Qbase = Qr + ((long)((b * NH + h) * NT) + qt * 64 + wid * 16) * 128;
  s16x8 qf[4];
#pragma unroll
  for (int i = 0; i < 4; i++) qf[i] = *(const s16x8*)(Qbase + (long)r * 128 + i * 32 + kg * 8);
  const u16* Kb = Kr + (long)(b * NKV + kvh) * NT * 128;
  const u16* Vb = Vr + (long)(b * NKV + kvh) * NT * 128;

  // staging index precompute
  int krr = tid >> 4, kcc = tid & 15;                 // K: row p*16+krr, chunk kcc
  int vsrem = lane & 3, vc2 = (lane >> 2) & 1, vs4l = lane >> 3;
  int vrow = (wid & 1) * 32 + vs4l * 4 + vsrem;       // V global row within tile
  int vs4 = (wid & 1) * 8 + vs4l;                     // vrow>>2
  int vd8b = (wid >> 1) * 4;                          // d8 = vd8b + p

  f32x4 o[8];
#pragma unroll
  for (int n = 0; n < 8; n++) o[n] = (f32x4){0.f, 0.f, 0.f, 0.f};
  float mrow[4] = {-1e30f, -1e30f, -1e30f, -1e30f};
  float lrow[4] = {0.f, 0.f, 0.f, 0.f};

  s16x8 kreg[4], vreg[4];
#pragma unroll
  for (int p = 0; p < 4; p++) {
    kreg[p] = *(const s16x8*)(Kb + (long)(p * 16 + krr) * 128 + kcc * 8);
    vreg[p] = *(const s16x8*)(Vb + (long)vrow * 128 + (vd8b + p) * 16 + vc2 * 8);
  }

  for (int kt = 0; kt < NT; kt += 64) {
    __syncthreads();  // A: all waves done reading previous tile
#pragma unroll
    for (int p = 0; p < 4; p++) {
      int krow = p * 16 + krr;
      *(s16x8*)(KsB + krow * 256 + ((kcc ^ (krow & 7)) << 4)) = kreg[p];
      *(s16x8*)(VsB + vs4 * 1056 + (vd8b + p) * 128 + vsrem * 32 + vc2 * 16) = vreg[p];
    }
    __syncthreads();  // B: publish
    // prefetch next tile into regs; flies under the whole compute phase
    int ktn = (kt + 64) & (NT - 1);
#pragma unroll
    for (int p = 0; p < 4; p++) {
      kreg[p] = *(const s16x8*)(Kb + (long)(ktn + p * 16 + krr) * 128 + kcc * 8);
      vreg[p] = *(const s16x8*)(Vb + (long)(ktn + vrow) * 128 + (vd8b + p) * 16 + vc2 * 8);
    }
    // S = Q K^T : each wave 16 q-rows x 64 kv
    f32x4 sc[4];
#pragma unroll
    for (int n = 0; n < 4; n++) sc[n] = (f32x4){0.f, 0.f, 0.f, 0.f};
#pragma unroll
    for (int i = 0; i < 4; i++) {
#pragma unroll
      for (int n = 0; n < 4; n++) {
        int row = n * 16 + r;
        s16x8 kf = *(const s16x8*)(KsB + row * 256 + (((i * 4 + kg) ^ (row & 7)) << 4));
        sc[n] = __builtin_amdgcn_mfma_f32_16x16x32_bf16(qf[i], kf, sc[n], 0, 0, 0);
      }
    }
    // online softmax
#pragma unroll
    for (int e = 0; e < 4; e++) {
      float mx = fmaxf(fmaxf(sc[0][e], sc[1][e]), fmaxf(sc[2][e], sc[3][e]));
#pragma unroll
      for (int msk = 1; msk < 16; msk <<= 1) mx = fmaxf(mx, __shfl_xor(mx, msk, 64));
      float pm = mx * scale;
      float mnew = fmaxf(mrow[e], pm);
      float corr = __expf(mrow[e] - mnew);
      mrow[e] = mnew;
      float rs = 0.f;
      int prow = wid * 16 + kg * 4 + e;
#pragma unroll
      for (int n = 0; n < 4; n++) {
        float p = __expf(sc[n][e] * scale - mnew);
        rs += p;
        int off = (prow * 128 + (n * 16 + r) * 2) ^ ((prow & 7) << 4);
        *(u16*)(PsB + off) = f2bf(p);
      }
#pragma unroll
      for (int msk = 1; msk < 16; msk <<= 1) rs += __shfl_xor(rs, msk, 64);
      lrow[e] = lrow[e] * corr + rs;
#pragma unroll
      for (int n = 0; n < 8; n++) o[n][e] *= corr;
    }
    // O += P V  (Ps wave-private: no barrier; V via hardware transpose read)
#pragma unroll
    for (int i = 0; i < 2; i++) {
      int prow = wid * 16 + r;
      s16x8 pf = *(const s16x8*)(PsB + prow * 128 + (((i * 4 + kg) ^ (prow & 7)) << 4));
#pragma unroll
      for (int half = 0; half < 2; half++) {
        u32x2 t0[4], t1[4];
#pragma unroll
        for (int nn = 0; nn < 4; nn++) {
          int n = half * 4 + nn;
          unsigned ad = vsb + (unsigned)((i * 8 + kg * 2) * 1056 + n * 128 + (lane & 15) * 8);
          asm volatile("ds_read_b64_tr_b16 %0, %1" : "=v"(t0[nn]) : "v"(ad));
          asm volatile("ds_read_b64_tr_b16 %0, %1 offset:1056" : "=v"(t1[nn]) : "v"(ad));
        }
        asm volatile("s_waitcnt lgkmcnt(0)" ::: "memory");
        __builtin_amdgcn_sched_barrier(0);
#pragma unroll
        for (int nn = 0; nn < 4; nn++) {
          int n = half * 4 + nn;
          s16x8 vf = __builtin_bit_cast(
              s16x8, (u32x4){t0[nn].x, t0[nn].y, t1[nn].x, t1[nn].y});
          o[n] = __builtin_amdgcn_mfma_f32_16x16x32_bf16(pf, vf, o[n], 0, 0, 0);
        }
      }
    }
  }
  // epilogue: normalize and store to [b*T + row][h*128 + d]
#pragma unroll
  for (int e = 0; e < 4; e++) {
    float inv = 1.0f / lrow[e];
    int row = qt * 64 + wid * 16 + kg * 4 + e;
    u16* orow = Ao + (long)(b * NT + row) * ND + h * 128;
#pragma unroll
    for (int n = 0; n < 8; n++) orow[n * 16 + r] = f2bf(o[n][e] * inv);
  }
}

// ---------------- launch ----------------
extern "C" void kernel_launch(void* const* d_in, const int* in_sizes, int n_in,
                              void* d_out, int out_size, void* d_ws, size_t ws_size,
                              hipStream_t stream) {
  const float* x  = (const float*)d_in[0];
  const float* wq = (const float*)d_in[1];
  const float* wk = (const float*)d_in[2];
  const float* wv = (const float*)d_in[3];
  const float* wo = (const float*)d_in[4];
  char* ws = (char*)d_ws;
  size_t off = 0;
  auto alloc = [&](size_t bytes) {
    char* p = ws + off;
    off += (bytes + 255) & ~(size_t)255;
    return p;
  };
  u16* xb    = (u16*)alloc((size_t)4096 * 2048 * 2);
  u16* wqkvb = (u16*)alloc((size_t)3072 * 2048 * 2);
  u16* wob   = (u16*)alloc((size_t)2048 * 2048 * 2);
  u16* qkv   = (u16*)alloc((size_t)4096 * 3072 * 2);
  float* cs  = (float*)alloc((size_t)2048 * 64 * 4);
  float* sn  = (float*)alloc((size_t)2048 * 64 * 4);
  u16* Qr    = (u16*)alloc((size_t)2 * 16 * 2048 * 128 * 2);
  u16* Kr    = (u16*)alloc((size_t)2 * 4 * 2048 * 128 * 2);
  u16* Vr    = (u16*)alloc((size_t)2 * 4 * 2048 * 128 * 2);
  u16* Ao    = qkv;  // qkv dead after rearrange; reuse as attention output [4096][2048]

  cvt_kernel<<<dim3(2048), dim3(256), 0, stream>>>(x, xb, 4096L * 2048 / 4);
  cvt_kernel<<<dim3(1024), dim3(256), 0, stream>>>(wq, wqkvb, 2048L * 2048 / 4);
  cvt_kernel<<<dim3(256), dim3(256), 0, stream>>>(wk, wqkvb + 2048L * 2048, 512L * 2048 / 4);
  cvt_kernel<<<dim3(256), dim3(256), 0, stream>>>(wv, wqkvb + 2560L * 2048, 512L * 2048 / 4);
  cvt_kernel<<<dim3(1024), dim3(256), 0, stream>>>(wo, wob, 2048L * 2048 / 4);
  rope_table_kernel<<<dim3(512), dim3(256), 0, stream>>>(cs, sn);
  gemm_bt_kernel<u16><<<dim3(32 * 24), dim3(256), 0, stream>>>(xb, wqkvb, qkv, 4096, 3072, 2048);
  rope_q_kernel<<<dim3(8192), dim3(256), 0, stream>>>(qkv, cs, sn, Qr);
  rope_k_kernel<<<dim3(2048), dim3(256), 0, stream>>>(qkv, cs, sn, Kr);
  copy_v_kernel<<<dim3(1024), dim3(256), 0, stream>>>(qkv, Vr);
  attn_kernel<<<dim3(1024), dim3(256), 0, stream>>>(Qr, Kr, Vr, Ao);
  gemm_bt_kernel<float><<<dim3(32 * 16), dim3(256), 0, stream>>>(Ao, wob, (float*)d_out, 4096, 2048, 2048);
}

// Round 6
// 325.855 us; speedup vs baseline: 1.5094x; 1.3415x over previous
//
#include <hip/hip_runtime.h>
#include <hip/hip_bf16.h>

typedef unsigned short u16;
typedef unsigned int u32;
typedef __attribute__((ext_vector_type(4))) float f32x4;
typedef __attribute__((ext_vector_type(16))) float f32x16;
typedef __attribute__((ext_vector_type(8))) short s16x8;
typedef __attribute__((ext_vector_type(2))) unsigned int u32x2;
typedef __attribute__((ext_vector_type(4))) unsigned int u32x4;

#define NB 2
#define NT 2048
#define ND 2048
#define NH 16
#define NKV 4
#define NHD 128
// 1/sqrt(128) * log2(e): folded into Q during rope so attn uses exp2 directly
#define QSC 0.1275174337f

__device__ __forceinline__ u16 f2bf(float f) {
  u32 u = __builtin_bit_cast(u32, f);
  u32 r = u + 0x7fffu + ((u >> 16) & 1u);
  return (u16)(r >> 16);
}
__device__ __forceinline__ float bf2f(u16 h) {
  return __builtin_bit_cast(float, (u32)h << 16);
}
__device__ __forceinline__ void store_c(float* p, float v) { *p = v; }
__device__ __forceinline__ void store_c(u16* p, float v) { *p = f2bf(v); }

__device__ __forceinline__ void gll16(const u16* g, u16* l) {
  __builtin_amdgcn_global_load_lds(
      (const __attribute__((address_space(1))) u32*)(g),
      (__attribute__((address_space(3))) u32*)(l), 16, 0, 0);
}

__device__ __forceinline__ f32x16 zero16() {
  f32x16 v;
#pragma unroll
  for (int i = 0; i < 16; i++) v[i] = 0.f;
  return v;
}
__device__ __forceinline__ float vmax16(f32x16 v) {
  float a = fmaxf(fmaxf(v[0], v[1]), fmaxf(v[2], v[3]));
  float b = fmaxf(fmaxf(v[4], v[5]), fmaxf(v[6], v[7]));
  float c = fmaxf(fmaxf(v[8], v[9]), fmaxf(v[10], v[11]));
  float d = fmaxf(fmaxf(v[12], v[13]), fmaxf(v[14], v[15]));
  return fmaxf(fmaxf(a, b), fmaxf(c, d));
}
__device__ __forceinline__ float vsum16(f32x16 v) {
  float a = (v[0] + v[1]) + (v[2] + v[3]);
  float b = (v[4] + v[5]) + (v[6] + v[7]);
  float c = (v[8] + v[9]) + (v[10] + v[11]);
  float d = (v[12] + v[13]) + (v[14] + v[15]);
  return (a + b) + (c + d);
}
__device__ __forceinline__ u32 cvtpk(float lo, float hi) {
  u32 w;
  asm("v_cvt_pk_bf16_f32 %0, %1, %2" : "=v"(w) : "v"(lo), "v"(hi));
  return w;
}

// ---------------- fused f32 -> bf16 conversion (x | wq|wk|wv | wo) ----------------
__global__ void cvt_all_kernel(const float* __restrict__ x, const float* __restrict__ wq,
                               const float* __restrict__ wk, const float* __restrict__ wv,
                               const float* __restrict__ wo, u16* __restrict__ dst) {
  long stride = (long)gridDim.x * blockDim.x;
  for (long i = (long)blockIdx.x * blockDim.x + threadIdx.x; i < 4718592L; i += stride) {
    const float* src;
    long off;
    if (i < 2097152L) { src = x; off = i; }
    else if (i < 3145728L) { src = wq; off = i - 2097152L; }
    else if (i < 3407872L) { src = wk; off = i - 3145728L; }
    else if (i < 3670016L) { src = wv; off = i - 3407872L; }
    else { src = wo; off = i - 3670016L; }
    float4 v = *(const float4*)(src + off * 4);
    ushort4 o;
    o.x = f2bf(v.x); o.y = f2bf(v.y); o.z = f2bf(v.z); o.w = f2bf(v.w);
    *(ushort4*)(dst + i * 4) = o;
  }
}

// ---------------- RoPE table ----------------
__global__ void rope_table_kernel(float* __restrict__ cs, float* __restrict__ sn) {
  int idx = blockIdx.x * blockDim.x + threadIdx.x;
  if (idx >= NT * 64) return;
  int t = idx >> 6, j = idx & 63;
  float invf = expf(-(float)(2 * j) * (9.210340371976184f / 128.0f)); // 10000^(-2j/128)
  float f = (float)t * invf;
  cs[idx] = cosf(f);
  sn[idx] = sinf(f);
}

// ---------------- GEMM: C[M][N] = A[M][K] * B[N][K]^T (m97 structure) ----------------
// VSPLIT: column blocks bn>=20 (V region of QKV) are written transposed into Vtg[b][kv][d][t]
template <typename OT, bool VSPLIT>
__global__ __launch_bounds__(256, 3)
void gemm_bt_kernel(const u16* __restrict__ A, const u16* __restrict__ Bm,
                    OT* __restrict__ C, u16* __restrict__ Vtg, int M, int N, int K) {
  __shared__ __align__(16) u16 As[128 * 32];  // [row][32] linear, 64B rows
  __shared__ __align__(16) u16 Bs[128 * 32];
  int nwg = gridDim.x;
  int bid = (blockIdx.x & 7) * (nwg >> 3) + (blockIdx.x >> 3);  // XCD swizzle (nwg%8==0)
  int ntn = N >> 7;
  int bm = bid / ntn, bn = bid % ntn;
  int tid = threadIdx.x;
  int lane = tid & 63;
  int wid = tid >> 6;
  int wm = wid >> 1, wn = wid & 1;  // 2x2 waves, each 64x64
  int r = lane & 15, kg = lane >> 4;
  const u16* Ag = A + (long)(bm * 128 + wid * 32 + (lane >> 2)) * K + (lane & 3) * 8;
  const u16* Bg = Bm + (long)(bn * 128 + wid * 32 + (lane >> 2)) * K + (lane & 3) * 8;
  char* AsB = (char*)As;
  char* BsB = (char*)Bs;
  u16* Ald0 = As + (wid * 32) * 32;
  u16* Ald1 = As + (wid * 32 + 16) * 32;
  u16* Bld0 = Bs + (wid * 32) * 32;
  u16* Bld1 = Bs + (wid * 32 + 16) * 32;
  f32x4 acc[4][4];
#pragma unroll
  for (int i = 0; i < 4; i++)
#pragma unroll
    for (int j = 0; j < 4; j++) acc[i][j] = (f32x4){0.f, 0.f, 0.f, 0.f};
  for (int k0 = 0; k0 < K; k0 += 32) {
    __syncthreads();
    gll16(Ag + k0, Ald0);
    gll16(Ag + 16 * K + k0, Ald1);
    gll16(Bg + k0, Bld0);
    gll16(Bg + 16 * K + k0, Bld1);
    __syncthreads();
    s16x8 af[4], bf[4];
#pragma unroll
    for (int i = 0; i < 4; i++) af[i] = *(const s16x8*)(AsB + (wm * 64 + i * 16 + r) * 64 + kg * 16);
#pragma unroll
    for (int j = 0; j < 4; j++) bf[j] = *(const s16x8*)(BsB + (wn * 64 + j * 16 + r) * 64 + kg * 16);
#pragma unroll
    for (int i = 0; i < 4; i++)
#pragma unroll
      for (int j = 0; j < 4; j++)
        acc[i][j] = __builtin_amdgcn_mfma_f32_16x16x32_bf16(af[i], bf[j], acc[i][j], 0, 0, 0);
  }
  // C/D layout: col = lane&15, row = (lane>>4)*4 + reg
  if (VSPLIT && bn >= 20) {
    // V region: scatter transposed into Vtg[(b*4+kv)*128 + d][t]
#pragma unroll
    for (int i = 0; i < 4; i++) {
      int row0 = bm * 128 + wm * 64 + i * 16 + kg * 4;
      int bb = row0 >> 11, t0 = row0 & 2047;
#pragma unroll
      for (int j = 0; j < 4; j++) {
        int col = bn * 128 + wn * 64 + j * 16 + r;
        int kvq = (col >> 7) - 20, d = col & 127;
        ushort4 vv;
        vv.x = f2bf(acc[i][j][0]); vv.y = f2bf(acc[i][j][1]);
        vv.z = f2bf(acc[i][j][2]); vv.w = f2bf(acc[i][j][3]);
        *(ushort4*)(Vtg + ((size_t)((bb * 4 + kvq) * 128 + d)) * 2048 + t0) = vv;
      }
    }
  } else {
#pragma unroll
    for (int i = 0; i < 4; i++) {
      int row0 = bm * 128 + wm * 64 + i * 16 + kg * 4;
#pragma unroll
      for (int j = 0; j < 4; j++) {
        int col = bn * 128 + wn * 64 + j * 16 + r;
#pragma unroll
        for (int e = 0; e < 4; e++) store_c(&C[(long)(row0 + e) * N + col], acc[i][j][e]);
      }
    }
  }
}

// ---------------- RoPE + rearrange (vectorized x2) ----------------
__global__ void rope_q_kernel(const u16* __restrict__ qkv, const float* __restrict__ cs,
                              const float* __restrict__ sn, u16* __restrict__ Qr) {
  int idx = blockIdx.x * blockDim.x + threadIdx.x;  // NB*NT*NH*32
  int j = (idx & 31) * 2;
  int h = (idx >> 5) & 15;
  int t = (idx >> 9) & 2047;
  int b = idx >> 20;
  const u16* row = qkv + (long)(b * NT + t) * 3072 + h * 128;
  u32 x1p = *(const u32*)(row + j);
  u32 x2p = *(const u32*)(row + j + 64);
  float2 cp = *(const float2*)(cs + t * 64 + j);
  float2 sp = *(const float2*)(sn + t * 64 + j);
  float x1a = bf2f((u16)x1p), x1b = bf2f((u16)(x1p >> 16));
  float x2a = bf2f((u16)x2p), x2b = bf2f((u16)(x2p >> 16));
  u16* orow = Qr + ((long)((b * NH + h) * NT + t)) * 128;
  u32 o1 = (u32)f2bf((x1a * cp.x - x2a * sp.x) * QSC) |
           ((u32)f2bf((x1b * cp.y - x2b * sp.y) * QSC) << 16);
  u32 o2 = (u32)f2bf((x2a * cp.x + x1a * sp.x) * QSC) |
           ((u32)f2bf((x2b * cp.y + x1b * sp.y) * QSC) << 16);
  *(u32*)(orow + j) = o1;
  *(u32*)(orow + j + 64) = o2;
}

__global__ void rope_k_kernel(const u16* __restrict__ qkv, const float* __restrict__ cs,
                              const float* __restrict__ sn, u16* __restrict__ Kr) {
  int idx = blockIdx.x * blockDim.x + threadIdx.x;  // NB*NT*NKV*32
  int j = (idx & 31) * 2;
  int kv = (idx >> 5) & 3;
  int t = (idx >> 7) & 2047;
  int b = idx >> 18;
  const u16* row = qkv + (long)(b * NT + t) * 3072 + 2048 + kv * 128;
  u32 x1p = *(const u32*)(row + j);
  u32 x2p = *(const u32*)(row + j + 64);
  float2 cp = *(const float2*)(cs + t * 64 + j);
  float2 sp = *(const float2*)(sn + t * 64 + j);
  float x1a = bf2f((u16)x1p), x1b = bf2f((u16)(x1p >> 16));
  float x2a = bf2f((u16)x2p), x2b = bf2f((u16)(x2p >> 16));
  u16* orow = Kr + ((long)((b * NKV + kv) * NT + t)) * 128;
  u32 o1 = (u32)f2bf(x1a * cp.x - x2a * sp.x) | ((u32)f2bf(x1b * cp.y - x2b * sp.y) << 16);
  u32 o2 = (u32)f2bf(x2a * cp.x + x1a * sp.x) | ((u32)f2bf(x2b * cp.y + x1b * sp.y) << 16);
  *(u32*)(orow + j) = o1;
  *(u32*)(orow + j + 64) = o2;
}

// ---------------- Flash attention: 32x32 swapped-QK, in-register softmax ----------------
// K LDS [64][128] + Vt LDS [128][64], XOR-swizzled ((row&7) on 16B cols), double-buffered.
// Per wave: 32 q-rows. Lane owns q = qbase + (lane&31); S'[kv][q] via mfma(K, Q).
__global__ __launch_bounds__(256, 2)
void attn_kernel(const u16* __restrict__ Qr, const u16* __restrict__ Kr,
                 const u16* __restrict__ Vtg, u16* __restrict__ Ao) {
  __shared__ __align__(16) u16 smem[32768];  // [buf][K|Vt][8192 u16] = 64 KB
  int g = blockIdx.x & 7;      // (b,kvh) -> one XCD each: K/V stays L2-resident
  int inner = blockIdx.x >> 3; // 0..63
  int b = g >> 2, kvh = g & 3;
  int h = kvh * 4 + (inner & 3);
  int qt = inner >> 2;         // 16 q-tiles of 128 rows
  int tid = threadIdx.x, lane = tid & 63, wid = tid >> 6;
  int rq = lane & 31, hi = lane >> 5;
  int cxor = (rq & 7) << 4;
  const u16* Kb = Kr + (size_t)(b * NKV + kvh) * NT * 128;
  const u16* Vb = Vtg + (size_t)(b * NKV + kvh) * 128 * NT;
  int qrow0 = qt * 128 + wid * 32;
  const u16* Qbase = Qr + ((size_t)((b * NH + h) * NT) + qrow0 + rq) * 128 + hi * 8;

  // stage tile 0
  {
    u16* kb = smem;
    u16* vb = smem + 8192;
#pragma unroll
    for (int pass = 0; pass < 4; pass++) {
      int krow = pass * 16 + wid * 4 + (lane >> 4);
      int kc = (lane & 15) ^ (krow & 7);
      gll16(Kb + ((size_t)krow << 7) + kc * 8, kb + pass * 2048 + wid * 512);
      int vrow = pass * 32 + wid * 8 + (lane >> 3);
      int vc = (lane & 7) ^ (vrow & 7);
      gll16(Vb + ((size_t)vrow << 11) + vc * 8, vb + pass * 2048 + wid * 512);
    }
  }
  // Q fragments: lane holds q-row (lane&31), k = ks*16 + hi*8 + j
  s16x8 qf[8];
#pragma unroll
  for (int ks = 0; ks < 8; ks++) qf[ks] = *(const s16x8*)(Qbase + ks * 16);

  f32x16 o[4];
#pragma unroll
  for (int db = 0; db < 4; db++) o[db] = zero16();
  float mrun = -1e30f, lrun = 0.f;

  __syncthreads();

#pragma unroll 1
  for (int kt = 0; kt < NT; kt += 64) {
    int buf = (kt >> 6) & 1;
    const char* kbB = (const char*)(smem + buf * 16384);
    const char* vbB = (const char*)(smem + buf * 16384 + 8192);
    if (kt + 64 < NT) {  // prefetch next tile into other buffer
      u16* kb = smem + (buf ^ 1) * 16384;
      u16* vb = kb + 8192;
#pragma unroll
      for (int pass = 0; pass < 4; pass++) {
        int krow = pass * 16 + wid * 4 + (lane >> 4);
        int kc = (lane & 15) ^ (krow & 7);
        gll16(Kb + ((size_t)(kt + 64 + krow) << 7) + kc * 8, kb + pass * 2048 + wid * 512);
        int vrow = pass * 32 + wid * 8 + (lane >> 3);
        int vc = (lane & 7) ^ (vrow & 7);
        gll16(Vb + ((size_t)vrow << 11) + (kt + 64) + vc * 8, vb + pass * 2048 + wid * 512);
      }
    }
    // ---- QK^T (swapped): s0 = kv[0:32), s1 = kv[32:64) ----
    f32x16 s0 = zero16(), s1 = zero16();
#pragma unroll
    for (int ks = 0; ks < 8; ks++) {
      int c = (ks * 2 + hi) << 4;
      s16x8 kf0 = *(const s16x8*)(kbB + rq * 256 + (c ^ cxor));
      s16x8 kf1 = *(const s16x8*)(kbB + (32 + rq) * 256 + (c ^ cxor));
      s0 = __builtin_amdgcn_mfma_f32_32x32x16_bf16(kf0, qf[ks], s0, 0, 0, 0);
      s1 = __builtin_amdgcn_mfma_f32_32x32x16_bf16(kf1, qf[ks], s1, 0, 0, 0);
    }
    // ---- online softmax, in-register (scores already in log2 units) ----
    float pm = fmaxf(vmax16(s0), vmax16(s1));
    pm = fmaxf(pm, __shfl_xor(pm, 32, 64));
    if (!__all(pm <= mrun + 8.0f)) {  // defer-max (T13)
      float corr = exp2f(mrun - pm);
      mrun = pm;
      lrun *= corr;
#pragma unroll
      for (int db = 0; db < 4; db++)
#pragma unroll
        for (int i = 0; i < 16; i++) o[db][i] *= corr;
    }
#pragma unroll
    for (int i = 0; i < 16; i++) s0[i] = exp2f(s0[i] - mrun);
#pragma unroll
    for (int i = 0; i < 16; i++) s1[i] = exp2f(s1[i] - mrun);
    lrun += vsum16(s0) + vsum16(s1);
    // ---- pack P to bf16 words; exchange across lane^32 to form PV B-frags ----
    u32 aw[16];
#pragma unroll
    for (int u = 0; u < 8; u++) {
      aw[u] = cvtpk(s0[2 * u], s0[2 * u + 1]);
      aw[8 + u] = cvtpk(s1[2 * u], s1[2 * u + 1]);
    }
#pragma unroll
    for (int base = 0; base < 16; base += 4) {
#pragma unroll
      for (int t = 0; t < 2; t++) {
        u32 X = aw[base + t], Y = aw[base + t + 2];
        u32 sx = __shfl_xor(X, 32, 64), sy = __shfl_xor(Y, 32, 64);
        aw[base + t] = hi ? sy : X;
        aw[base + t + 2] = hi ? Y : sx;
      }
    }
    // ---- PV: o = Vt x P (O^T: rows=d, cols=q) ----
#pragma unroll
    for (int s = 0; s < 4; s++) {
      s16x8 pf = __builtin_bit_cast(
          s16x8, (u32x4){aw[s * 4], aw[s * 4 + 1], aw[s * 4 + 2], aw[s * 4 + 3]});
      int c = (s * 2 + hi) << 4;
#pragma unroll
      for (int db = 0; db < 4; db++) {
        s16x8 vf = *(const s16x8*)(vbB + (db * 32 + rq) * 128 + (c ^ cxor));
        o[db] = __builtin_amdgcn_mfma_f32_32x32x16_bf16(vf, pf, o[db], 0, 0, 0);
      }
    }
    __syncthreads();
  }
  // ---- epilogue: normalize, LDS bounce to coalesce, store Ao[b*T+q][h*128+d] ----
  float lt = lrun + __shfl_xor(lrun, 32, 64);
  float inv = 1.0f / lt;
  char* eb = (char*)smem + wid * 8192;  // 32 q x 256 B per wave
#pragma unroll
  for (int db = 0; db < 4; db++)
#pragma unroll
    for (int qd = 0; qd < 4; qd++) {
      u32 w0 = cvtpk(o[db][qd * 4 + 0] * inv, o[db][qd * 4 + 1] * inv);
      u32 w1 = cvtpk(o[db][qd * 4 + 2] * inv, o[db][qd * 4 + 3] * inv);
      *(u32x2*)(eb + rq * 256 + (db * 32 + qd * 8 + hi * 4) * 2) = (u32x2){w0, w1};
    }
  __syncthreads();
  // each lane copies 128 B: q-row qq, half hf -> 8 x 16 B  (r5 fix: was 4 x 16 B @ 32-B stride)
  int qq = lane >> 1, hf = lane & 1;
  size_t orow = ((size_t)(b * NT) + qrow0 + qq) * 2048 + h * 128 + hf * 64;
#pragma unroll
  for (int i = 0; i < 8; i++) {
    u32x4 vv = *(const u32x4*)(eb + qq * 256 + hf * 128 + i * 16);
    *(u32x4*)(Ao + orow + i * 8) = vv;
  }
}

// ---------------- launch ----------------
extern "C" void kernel_launch(void* const* d_in, const int* in_sizes, int n_in,
                              void* d_out, int out_size, void* d_ws, size_t ws_size,
                              hipStream_t stream) {
  const float* x  = (const float*)d_in[0];
  const float* wq = (const float*)d_in[1];
  const float* wk = (const float*)d_in[2];
  const float* wv = (const float*)d_in[3];
  const float* wo = (const float*)d_in[4];
  char* ws = (char*)d_ws;
  size_t off = 0;
  auto alloc = [&](size_t bytes) {
    char* p = ws + off;
    off += (bytes + 255) & ~(size_t)255;
    return p;
  };
  u16* xb    = (u16*)alloc((size_t)4096 * 2048 * 2);   // contiguous with wqkvb, wob
  u16* wqkvb = (u16*)alloc((size_t)3072 * 2048 * 2);
  u16* wob   = (u16*)alloc((size_t)2048 * 2048 * 2);
  u16* qkv   = (u16*)alloc((size_t)4096 * 3072 * 2);
  float* cs  = (float*)alloc((size_t)2048 * 64 * 4);
  float* sn  = (float*)alloc((size_t)2048 * 64 * 4);
  u16* Qr    = (u16*)alloc((size_t)2 * 16 * 2048 * 128 * 2);
  u16* Kr    = (u16*)alloc((size_t)2 * 4 * 2048 * 128 * 2);
  u16* Vtg   = (u16*)alloc((size_t)2 * 4 * 128 * 2048 * 2);
  u16* Ao    = qkv;  // qkv dead after rope; reuse as attention output [4096][2048]

  cvt_all_kernel<<<dim3(2048), dim3(256), 0, stream>>>(x, wq, wk, wv, wo, xb);
  rope_table_kernel<<<dim3(512), dim3(256), 0, stream>>>(cs, sn);
  gemm_bt_kernel<u16, true><<<dim3(768), dim3(256), 0, stream>>>(
      xb, wqkvb, qkv, Vtg, 4096, 3072, 2048);
  rope_q_kernel<<<dim3(8192), dim3(256), 0, stream>>>(qkv, cs, sn, Qr);
  rope_k_kernel<<<dim3(2048), dim3(256), 0, stream>>>(qkv, cs, sn, Kr);
  attn_kernel<<<dim3(512), dim3(256), 0, stream>>>(Qr, Kr, Vtg, Ao);
  gemm_bt_kernel<float, false><<<dim3(512), dim3(256), 0, stream>>>(
      Ao, wob, (float*)d_out, nullptr, 4096, 2048, 2048);
}